// Round 6
// baseline (43.912 us; speedup 1.0000x reference)
//
#include <hip/hip_runtime.h>

// Chamfer NN squared distances via MFMA (f16 hi/lo emulation), fused single kernel.
//
// d(q,r) = |q|^2 + |r|^2 - 2 q.r packed into ONE mfma_f32_32x32x16_f16 (13 K-slots):
//   A (query row, g=0): {-2hx,-2hy,-2hz,-2hx,-2hy,-2hz,-2lx,-2ly}
//   A (query row, g=1): {-2lz, 1, 1, sh, sl, 0, 0, 0}
//   B (ref col,   g=0): { hx,  hy,  hz,  lx,  ly,  lz, hx, hy}
//   B (ref col,   g=1): { hz,  sh,  sl,  1,  1, 0, 0, 0}
// => D = -2(h.H + h.L + l.H) + |r|^2 + |q|^2  (error ~1e-4, threshold 0.12)
//
// Occupancy-first layout (round-5 lesson: 2 waves/SIMD = latency death):
//   TPB=256 (4 waves), 64 query rows per wave (2 A-frags), RPB=256.
//   Ref dim split SPLIT=2 across blocks -> 1024 blocks = 4 blocks/CU = 4 waves/SIMD.
//   CHUNK=1024 refs per LDS pass, split-half layout (2 x 16 KB, 16 B stride).
//   Inner step: 1 ds_read_b128 -> 2 MFMAs -> 32 v_min. Live regs ~104 < 128 cap.
//   SPLIT partials combined via atomicMin on int view (distances >= 0).

typedef _Float16 v8h  __attribute__((ext_vector_type(8)));
typedef float    v16f __attribute__((ext_vector_type(16)));

constexpr int TPB   = 256;        // 4 waves
constexpr int RPW   = 64;         // rows per wave (2 A-fragments)
constexpr int RPB   = 4 * RPW;    // 256 rows per block
constexpr int CHUNK = 1024;       // ref points per LDS pass (2 x 16 KB halves)
constexpr int SPLIT = 2;          // ref-dim split for occupancy

__device__ __forceinline__ void split3(float x, float y, float z,
    _Float16& hx, _Float16& hy, _Float16& hz,
    _Float16& lx, _Float16& ly, _Float16& lz,
    _Float16& sh, _Float16& sl)
{
    const float s = fmaf(z, z, fmaf(y, y, x * x));
    hx = (_Float16)x; hy = (_Float16)y; hz = (_Float16)z;
    lx = (_Float16)(x - (float)hx);
    ly = (_Float16)(y - (float)hy);
    lz = (_Float16)(z - (float)hz);
    sh = (_Float16)s;
    sl = (_Float16)(s - (float)sh);
}

__device__ __forceinline__ v8h packA(const float* __restrict__ qb, int row, int g)
{
    const float x = qb[(size_t)row * 3 + 0];
    const float y = qb[(size_t)row * 3 + 1];
    const float z = qb[(size_t)row * 3 + 2];
    _Float16 hx, hy, hz, lx, ly, lz, sh, sl;
    split3(x, y, z, hx, hy, hz, lx, ly, lz, sh, sl);
    const _Float16 nhx = (_Float16)(-2.f * x);
    const _Float16 nhy = (_Float16)(-2.f * y);
    const _Float16 nhz = (_Float16)(-2.f * z);
    const _Float16 nlx = (_Float16)(-2.f * (x - (float)hx));
    const _Float16 nly = (_Float16)(-2.f * (y - (float)hy));
    const _Float16 nlz = (_Float16)(-2.f * (z - (float)hz));
    const _Float16 one = (_Float16)1.f, zz = (_Float16)0.f;
    const v8h A0 = {nhx, nhy, nhz, nhx, nhy, nhz, nlx, nly};
    const v8h A1 = {nlz, one, one, sh, sl, zz, zz, zz};
    return g ? A1 : A0;
}

__device__ __forceinline__ void packB(float x, float y, float z, uint4& h0, uint4& h1)
{
    _Float16 hx, hy, hz, lx, ly, lz, sh, sl;
    split3(x, y, z, hx, hy, hz, lx, ly, lz, sh, sl);
    const _Float16 one = (_Float16)1.f, zz = (_Float16)0.f;
    const v8h B0 = {hx, hy, hz, lx, ly, lz, hx, hy};
    const v8h B1 = {hz, sh, sl, one, one, zz, zz, zz};
    h0 = __builtin_bit_cast(uint4, B0);
    h1 = __builtin_bit_cast(uint4, B1);
}

__global__ __launch_bounds__(TPB, 4) void nnd_mfma2(
    const float* __restrict__ p1, const float* __restrict__ p2,
    float* __restrict__ out, int B, int N, int M)
{
    const int dir = blockIdx.z >> 1;     // 0: q=p1,r=p2 (dist1); 1: swapped
    const int s   = blockIdx.z & 1;      // ref-dim split index
    const int b   = blockIdx.y;
    const float* __restrict__ q = dir ? p2 : p1;
    const float* __restrict__ r = dir ? p1 : p2;
    const int Nq = dir ? M : N;
    const int Nr = dir ? N : M;
    float* __restrict__ o = out + (dir ? (size_t)B * N : 0) + (size_t)b * Nq;

    const int tid  = threadIdx.x;
    const int w    = tid >> 6;
    const int lane = tid & 63;
    const int c    = lane & 31;          // MFMA row (A) / col (B) within tile
    const int g    = lane >> 5;          // k-half
    const int row0 = blockIdx.x * RPB + w * RPW;

    const float* qb = q + (size_t)b * Nq * 3;
    const v8h a0 = packA(qb, row0 + c, g);
    const v8h a1 = packA(qb, row0 + 32 + c, g);

    v16f zc;
#pragma unroll
    for (int i = 0; i < 16; ++i) zc[i] = 0.f;
    float rm0[16], rm1[16];
#pragma unroll
    for (int i = 0; i < 16; ++i) { rm0[i] = 3.0e38f; rm1[i] = 3.0e38f; }

    __shared__ uint4 sb[2 * CHUNK];      // [half][slot], 16 B stride per half
    const float* rb = r + (size_t)b * Nr * 3;
    const uint4* sbase = sb + (g ? CHUNK : 0);

    const int r0 = s * (Nr / SPLIT);
    const int r1 = r0 + Nr / SPLIT;

    for (int ts = r0; ts < r1; ts += CHUNK) {
        __syncthreads();                 // previous chunk fully consumed
        // stage + pack CHUNK refs; slots permuted so both LDS writes are
        // consecutive-16B across the wave (conflict-free). Slot order within
        // a chunk is irrelevant for the min reduction.
#pragma unroll
        for (int rd = 0; rd < CHUNK / (2 * TPB); ++rd) {
            const float2* s2 = (const float2*)(rb + (size_t)(ts + rd * 2 * TPB) * 3);
            const float2 A  = s2[3 * tid + 0];
            const float2 C2 = s2[3 * tid + 1];
            const float2 E  = s2[3 * tid + 2];
            uint4 p0h0, p0h1, p1h0, p1h1;
            packB(A.x, A.y, C2.x, p0h0, p0h1);
            packB(C2.y, E.x, E.y, p1h0, p1h1);
            const int base = rd * 2 * TPB;
            sb[base + tid]               = p0h0;
            sb[base + TPB + tid]         = p1h0;
            sb[CHUNK + base + tid]       = p0h1;
            sb[CHUNK + base + TPB + tid] = p1h1;
        }
        __syncthreads();

#pragma unroll 8
        for (int st = 0; st < CHUNK / 32; ++st) {
            const v8h bf = __builtin_bit_cast(v8h, sbase[st * 32 + c]);
            const v16f d0 = __builtin_amdgcn_mfma_f32_32x32x16_f16(a0, bf, zc, 0, 0, 0);
            const v16f d1 = __builtin_amdgcn_mfma_f32_32x32x16_f16(a1, bf, zc, 0, 0, 0);
#pragma unroll
            for (int i = 0; i < 16; ++i) {
                rm0[i] = fminf(rm0[i], d0[i]);
                rm1[i] = fminf(rm1[i], d1[i]);
            }
        }
    }

    // min over the 32 columns (bits 0-4); g (bit 5) untouched
#pragma unroll
    for (int i = 0; i < 16; ++i) {
        float v0 = rm0[i], v1 = rm1[i];
        v0 = fminf(v0, __shfl_xor(v0, 1));  v1 = fminf(v1, __shfl_xor(v1, 1));
        v0 = fminf(v0, __shfl_xor(v0, 2));  v1 = fminf(v1, __shfl_xor(v1, 2));
        v0 = fminf(v0, __shfl_xor(v0, 4));  v1 = fminf(v1, __shfl_xor(v1, 4));
        v0 = fminf(v0, __shfl_xor(v0, 8));  v1 = fminf(v1, __shfl_xor(v1, 8));
        v0 = fminf(v0, __shfl_xor(v0, 16)); v1 = fminf(v1, __shfl_xor(v1, 16));
        rm0[i] = v0; rm1[i] = v1;
    }
    if (c == 0) {
#pragma unroll
        for (int i = 0; i < 16; ++i) {
            const int rr = (i & 3) + 8 * (i >> 2) + 4 * g;  // verified C layout
            atomicMin((int*)&o[row0 + rr],      __float_as_int(rm0[i]));
            atomicMin((int*)&o[row0 + 32 + rr], __float_as_int(rm1[i]));
        }
    }
}

// ---------------- fallback: round-3 identity-folded VALU kernel ----------------
constexpr int FTPB   = 256;
constexpr int FIPT   = 4;
constexpr int FTILE  = 512;
constexpr int FSPLIT = 8;

__global__ __launch_bounds__(FTPB, 4) void nnd_fold(
    const float* __restrict__ p1, const float* __restrict__ p2,
    float* __restrict__ out, int B, int N, int M)
{
    const int z   = blockIdx.z;
    const int dir = z / FSPLIT;
    const int s   = z % FSPLIT;
    const int b   = blockIdx.y;

    const float* __restrict__ q = dir ? p2 : p1;
    const float* __restrict__ r = dir ? p1 : p2;
    const int Nq = dir ? M : N;
    const int Nr = dir ? N : M;
    float* __restrict__ o = out + (dir ? (size_t)B * N : 0) + (size_t)b * Nq;

    const int tid = threadIdx.x;
    const float* qb = q + (size_t)b * Nq * 3;
    float qx[FIPT], qy[FIPT], qz[FIPT], qs[FIPT], mn[FIPT];
    int   qi[FIPT];
#pragma unroll
    for (int i = 0; i < FIPT; ++i) {
        qi[i] = blockIdx.x * (FTPB * FIPT) + i * FTPB + tid;
        if (qi[i] < Nq) {
            qx[i] = qb[qi[i] * 3 + 0]; qy[i] = qb[qi[i] * 3 + 1]; qz[i] = qb[qi[i] * 3 + 2];
        } else { qx[i] = qy[i] = qz[i] = 0.f; }
        float sq = qx[i] * qx[i];
        sq = fmaf(qy[i], qy[i], sq); sq = fmaf(qz[i], qz[i], sq);
        qs[i] = sq; mn[i] = 3.0e38f;
    }
    const int per = (Nr + FSPLIT - 1) / FSPLIT;
    const int r0 = s * per, r1 = min(Nr, r0 + per);
    __shared__ float4 shm[FTILE];
    const float* rb = r + (size_t)b * Nr * 3;
    for (int ts = r0; ts < r1; ts += FTILE) {
        const int npts = min(FTILE, r1 - ts);
        __syncthreads();
        if (npts == FTILE && ((((size_t)b * Nr + (size_t)ts) * 3) & 1) == 0) {
            const float2* src = (const float2*)(rb + (size_t)ts * 3);
            float2 a = src[3 * tid + 0], c2 = src[3 * tid + 1], e = src[3 * tid + 2];
            float s0 = a.x * a.x; s0 = fmaf(a.y, a.y, s0); s0 = fmaf(c2.x, c2.x, s0);
            float s1 = c2.y * c2.y; s1 = fmaf(e.x, e.x, s1); s1 = fmaf(e.y, e.y, s1);
            shm[2 * tid + 0] = make_float4(-2.f * a.x, -2.f * a.y, -2.f * c2.x, s0);
            shm[2 * tid + 1] = make_float4(-2.f * c2.y, -2.f * e.x, -2.f * e.y, s1);
        } else {
#pragma unroll
            for (int k = 0; k < 2; ++k) {
                const int pl = 2 * tid + k;
                float4 v = make_float4(0.f, 0.f, 0.f, 3.0e38f);
                if (pl < npts) {
                    const float* pp = rb + (size_t)(ts + pl) * 3;
                    float sq = pp[0] * pp[0];
                    sq = fmaf(pp[1], pp[1], sq); sq = fmaf(pp[2], pp[2], sq);
                    v = make_float4(-2.f * pp[0], -2.f * pp[1], -2.f * pp[2], sq);
                }
                shm[pl] = v;
            }
        }
        __syncthreads();
#pragma unroll 8
        for (int j = 0; j < FTILE; ++j) {
            const float4 p = shm[j];
#pragma unroll
            for (int i = 0; i < FIPT; ++i) {
                float t = fmaf(p.x, qx[i], p.w);
                t = fmaf(p.y, qy[i], t);
                t = fmaf(p.z, qz[i], t);
                mn[i] = fminf(mn[i], t);
            }
        }
    }
#pragma unroll
    for (int i = 0; i < FIPT; ++i)
        if (qi[i] < Nq) atomicMin((int*)&o[qi[i]], __float_as_int(mn[i] + qs[i]));
}

extern "C" void kernel_launch(void* const* d_in, const int* in_sizes, int n_in,
                              void* d_out, int out_size, void* d_ws, size_t ws_size,
                              hipStream_t stream) {
    const float* p1 = (const float*)d_in[0];
    const float* p2 = (const float*)d_in[1];
    float* out = (float*)d_out;

    const int B = 16;
    const int N = in_sizes[0] / (B * 3);
    const int M = in_sizes[1] / (B * 3);

    // init outputs to large positive float (0x7f7f7f7f ~ 3.39e38) for atomicMin
    hipMemsetAsync(d_out, 0x7f, (size_t)out_size * sizeof(float), stream);

    const bool mfma_ok = (N == M) && (N % RPB == 0) && ((N / SPLIT) % CHUNK == 0);

    if (mfma_ok) {
        dim3 grid(N / RPB, B, 2 * SPLIT);
        nnd_mfma2<<<grid, TPB, 0, stream>>>(p1, p2, out, B, N, M);
    } else {
        const int qmax = (N > M) ? N : M;
        dim3 grid((qmax + FTPB * FIPT - 1) / (FTPB * FIPT), B, 2 * FSPLIT);
        nnd_fold<<<grid, FTPB, 0, stream>>>(p1, p2, out, B, N, M);
    }
}

// Round 7
// 37.056 us; speedup vs baseline: 1.1850x; 1.1850x over previous
//
#include <hip/hip_runtime.h>

// Chamfer NN squared distances via MFMA (f16 hi/lo emulation), fused single kernel.
//
// d(q,r) = |q|^2 + |r|^2 - 2 q.r packed into ONE mfma_f32_32x32x16_f16 (13 K-slots):
//   A (query row, g=0): {-2hx,-2hy,-2hz,-2hx,-2hy,-2hz,-2lx,-2ly}
//   A (query row, g=1): {-2lz, 1, 1, sh, sl, 0, 0, 0}
//   B (ref col,   g=0): { hx,  hy,  hz,  lx,  ly,  lz, hx, hy}
//   B (ref col,   g=1): { hz,  sh,  sl,  1,  1, 0, 0, 0}
// => D = -2(h.H + h.L + l.H) + |r|^2 + |q|^2  (error ~1e-4, threshold 0.12)
//
// Round-6 lesson: __launch_bounds__(256,4) is only a MINIMUM; the allocator
// squeezed to 64 VGPR chasing 8 waves/EU (impossible: 32 KB LDS caps at
// 4 blocks/CU = 4 waves/EU) and spilled the 32 accumulators to scratch
// (WRITE_SIZE 33 MB, both pipes <30%). Fix: amdgpu_waves_per_eu(4,4) pins
// exactly 4 waves/EU -> full 128-VGPR budget, no spills.
//
// Layout: TPB=256 (4 waves), 64 query rows/wave (2 A-frags), RPB=256 rows/block.
// Ref dim split SPLIT=2 -> 1024 blocks = 4 blocks/CU. CHUNK=1024 refs per LDS
// pass, split-half layout (2 x 16 KB, 16 B stride = 2-way aliasing, free).
// Inner step: 1 ds_read_b128 -> 2 MFMAs -> 32 v_min. Partials via atomicMin.

typedef _Float16 v8h  __attribute__((ext_vector_type(8)));
typedef float    v16f __attribute__((ext_vector_type(16)));

constexpr int TPB   = 256;        // 4 waves
constexpr int RPW   = 64;         // rows per wave (2 A-fragments)
constexpr int RPB   = 4 * RPW;    // 256 rows per block
constexpr int CHUNK = 1024;       // ref points per LDS pass (2 x 16 KB halves)
constexpr int SPLIT = 2;          // ref-dim split for occupancy

__device__ __forceinline__ void split3(float x, float y, float z,
    _Float16& hx, _Float16& hy, _Float16& hz,
    _Float16& lx, _Float16& ly, _Float16& lz,
    _Float16& sh, _Float16& sl)
{
    const float s = fmaf(z, z, fmaf(y, y, x * x));
    hx = (_Float16)x; hy = (_Float16)y; hz = (_Float16)z;
    lx = (_Float16)(x - (float)hx);
    ly = (_Float16)(y - (float)hy);
    lz = (_Float16)(z - (float)hz);
    sh = (_Float16)s;
    sl = (_Float16)(s - (float)sh);
}

__device__ __forceinline__ v8h packA(const float* __restrict__ qb, int row, int g)
{
    const float x = qb[(size_t)row * 3 + 0];
    const float y = qb[(size_t)row * 3 + 1];
    const float z = qb[(size_t)row * 3 + 2];
    _Float16 hx, hy, hz, lx, ly, lz, sh, sl;
    split3(x, y, z, hx, hy, hz, lx, ly, lz, sh, sl);
    const _Float16 nhx = (_Float16)(-2.f * x);
    const _Float16 nhy = (_Float16)(-2.f * y);
    const _Float16 nhz = (_Float16)(-2.f * z);
    const _Float16 nlx = (_Float16)(-2.f * (x - (float)hx));
    const _Float16 nly = (_Float16)(-2.f * (y - (float)hy));
    const _Float16 nlz = (_Float16)(-2.f * (z - (float)hz));
    const _Float16 one = (_Float16)1.f, zz = (_Float16)0.f;
    const v8h A0 = {nhx, nhy, nhz, nhx, nhy, nhz, nlx, nly};
    const v8h A1 = {nlz, one, one, sh, sl, zz, zz, zz};
    return g ? A1 : A0;
}

__device__ __forceinline__ void packB(float x, float y, float z, uint4& h0, uint4& h1)
{
    _Float16 hx, hy, hz, lx, ly, lz, sh, sl;
    split3(x, y, z, hx, hy, hz, lx, ly, lz, sh, sl);
    const _Float16 one = (_Float16)1.f, zz = (_Float16)0.f;
    const v8h B0 = {hx, hy, hz, lx, ly, lz, hx, hy};
    const v8h B1 = {hz, sh, sl, one, one, zz, zz, zz};
    h0 = __builtin_bit_cast(uint4, B0);
    h1 = __builtin_bit_cast(uint4, B1);
}

__global__ __launch_bounds__(TPB)
__attribute__((amdgpu_waves_per_eu(4, 4)))
void nnd_mfma3(
    const float* __restrict__ p1, const float* __restrict__ p2,
    float* __restrict__ out, int B, int N, int M)
{
    const int dir = blockIdx.z >> 1;     // 0: q=p1,r=p2 (dist1); 1: swapped
    const int s   = blockIdx.z & 1;      // ref-dim split index
    const int b   = blockIdx.y;
    const float* __restrict__ q = dir ? p2 : p1;
    const float* __restrict__ r = dir ? p1 : p2;
    const int Nq = dir ? M : N;
    const int Nr = dir ? N : M;
    float* __restrict__ o = out + (dir ? (size_t)B * N : 0) + (size_t)b * Nq;

    const int tid  = threadIdx.x;
    const int w    = tid >> 6;
    const int lane = tid & 63;
    const int c    = lane & 31;          // MFMA row (A) / col (B) within tile
    const int g    = lane >> 5;          // k-half
    const int row0 = blockIdx.x * RPB + w * RPW;

    const float* qb = q + (size_t)b * Nq * 3;
    const v8h a0 = packA(qb, row0 + c, g);
    const v8h a1 = packA(qb, row0 + 32 + c, g);

    v16f zc;
#pragma unroll
    for (int i = 0; i < 16; ++i) zc[i] = 0.f;
    float rm0[16], rm1[16];
#pragma unroll
    for (int i = 0; i < 16; ++i) { rm0[i] = 3.0e38f; rm1[i] = 3.0e38f; }

    __shared__ uint4 sb[2 * CHUNK];      // [half][slot], 16 B stride per half
    const float* rb = r + (size_t)b * Nr * 3;
    const uint4* sbase = sb + (g ? CHUNK : 0);

    const int r0 = s * (Nr / SPLIT);
    const int r1 = r0 + Nr / SPLIT;

    for (int ts = r0; ts < r1; ts += CHUNK) {
        __syncthreads();                 // previous chunk fully consumed
        // stage + pack CHUNK refs; slots permuted so both LDS writes are
        // consecutive-16B across the wave (conflict-free). Slot order within
        // a chunk is irrelevant for the min reduction.
#pragma unroll
        for (int rd = 0; rd < CHUNK / (2 * TPB); ++rd) {
            const float2* s2 = (const float2*)(rb + (size_t)(ts + rd * 2 * TPB) * 3);
            const float2 A  = s2[3 * tid + 0];
            const float2 C2 = s2[3 * tid + 1];
            const float2 E  = s2[3 * tid + 2];
            uint4 p0h0, p0h1, p1h0, p1h1;
            packB(A.x, A.y, C2.x, p0h0, p0h1);
            packB(C2.y, E.x, E.y, p1h0, p1h1);
            const int base = rd * 2 * TPB;
            sb[base + tid]               = p0h0;
            sb[base + TPB + tid]         = p1h0;
            sb[CHUNK + base + tid]       = p0h1;
            sb[CHUNK + base + TPB + tid] = p1h1;
        }
        __syncthreads();

#pragma unroll 4
        for (int st = 0; st < CHUNK / 32; ++st) {
            const v8h bf = __builtin_bit_cast(v8h, sbase[st * 32 + c]);
            const v16f d0 = __builtin_amdgcn_mfma_f32_32x32x16_f16(a0, bf, zc, 0, 0, 0);
            const v16f d1 = __builtin_amdgcn_mfma_f32_32x32x16_f16(a1, bf, zc, 0, 0, 0);
#pragma unroll
            for (int i = 0; i < 16; ++i) {
                rm0[i] = fminf(rm0[i], d0[i]);
                rm1[i] = fminf(rm1[i], d1[i]);
            }
        }
    }

    // min over the 32 columns (bits 0-4); g (bit 5) untouched
#pragma unroll
    for (int i = 0; i < 16; ++i) {
        float v0 = rm0[i], v1 = rm1[i];
        v0 = fminf(v0, __shfl_xor(v0, 1));  v1 = fminf(v1, __shfl_xor(v1, 1));
        v0 = fminf(v0, __shfl_xor(v0, 2));  v1 = fminf(v1, __shfl_xor(v1, 2));
        v0 = fminf(v0, __shfl_xor(v0, 4));  v1 = fminf(v1, __shfl_xor(v1, 4));
        v0 = fminf(v0, __shfl_xor(v0, 8));  v1 = fminf(v1, __shfl_xor(v1, 8));
        v0 = fminf(v0, __shfl_xor(v0, 16)); v1 = fminf(v1, __shfl_xor(v1, 16));
        rm0[i] = v0; rm1[i] = v1;
    }
    if (c == 0) {
#pragma unroll
        for (int i = 0; i < 16; ++i) {
            const int rr = (i & 3) + 8 * (i >> 2) + 4 * g;  // verified C layout
            atomicMin((int*)&o[row0 + rr],      __float_as_int(rm0[i]));
            atomicMin((int*)&o[row0 + 32 + rr], __float_as_int(rm1[i]));
        }
    }
}

// ---------------- fallback: round-3 identity-folded VALU kernel ----------------
constexpr int FTPB   = 256;
constexpr int FIPT   = 4;
constexpr int FTILE  = 512;
constexpr int FSPLIT = 8;

__global__ __launch_bounds__(FTPB, 4) void nnd_fold(
    const float* __restrict__ p1, const float* __restrict__ p2,
    float* __restrict__ out, int B, int N, int M)
{
    const int z   = blockIdx.z;
    const int dir = z / FSPLIT;
    const int s   = z % FSPLIT;
    const int b   = blockIdx.y;

    const float* __restrict__ q = dir ? p2 : p1;
    const float* __restrict__ r = dir ? p1 : p2;
    const int Nq = dir ? M : N;
    const int Nr = dir ? N : M;
    float* __restrict__ o = out + (dir ? (size_t)B * N : 0) + (size_t)b * Nq;

    const int tid = threadIdx.x;
    const float* qb = q + (size_t)b * Nq * 3;
    float qx[FIPT], qy[FIPT], qz[FIPT], qs[FIPT], mn[FIPT];
    int   qi[FIPT];
#pragma unroll
    for (int i = 0; i < FIPT; ++i) {
        qi[i] = blockIdx.x * (FTPB * FIPT) + i * FTPB + tid;
        if (qi[i] < Nq) {
            qx[i] = qb[qi[i] * 3 + 0]; qy[i] = qb[qi[i] * 3 + 1]; qz[i] = qb[qi[i] * 3 + 2];
        } else { qx[i] = qy[i] = qz[i] = 0.f; }
        float sq = qx[i] * qx[i];
        sq = fmaf(qy[i], qy[i], sq); sq = fmaf(qz[i], qz[i], sq);
        qs[i] = sq; mn[i] = 3.0e38f;
    }
    const int per = (Nr + FSPLIT - 1) / FSPLIT;
    const int r0 = s * per, r1 = min(Nr, r0 + per);
    __shared__ float4 shm[FTILE];
    const float* rb = r + (size_t)b * Nr * 3;
    for (int ts = r0; ts < r1; ts += FTILE) {
        const int npts = min(FTILE, r1 - ts);
        __syncthreads();
        if (npts == FTILE && ((((size_t)b * Nr + (size_t)ts) * 3) & 1) == 0) {
            const float2* src = (const float2*)(rb + (size_t)ts * 3);
            float2 a = src[3 * tid + 0], c2 = src[3 * tid + 1], e = src[3 * tid + 2];
            float s0 = a.x * a.x; s0 = fmaf(a.y, a.y, s0); s0 = fmaf(c2.x, c2.x, s0);
            float s1 = c2.y * c2.y; s1 = fmaf(e.x, e.x, s1); s1 = fmaf(e.y, e.y, s1);
            shm[2 * tid + 0] = make_float4(-2.f * a.x, -2.f * a.y, -2.f * c2.x, s0);
            shm[2 * tid + 1] = make_float4(-2.f * c2.y, -2.f * e.x, -2.f * e.y, s1);
        } else {
#pragma unroll
            for (int k = 0; k < 2; ++k) {
                const int pl = 2 * tid + k;
                float4 v = make_float4(0.f, 0.f, 0.f, 3.0e38f);
                if (pl < npts) {
                    const float* pp = rb + (size_t)(ts + pl) * 3;
                    float sq = pp[0] * pp[0];
                    sq = fmaf(pp[1], pp[1], sq); sq = fmaf(pp[2], pp[2], sq);
                    v = make_float4(-2.f * pp[0], -2.f * pp[1], -2.f * pp[2], sq);
                }
                shm[pl] = v;
            }
        }
        __syncthreads();
#pragma unroll 8
        for (int j = 0; j < FTILE; ++j) {
            const float4 p = shm[j];
#pragma unroll
            for (int i = 0; i < FIPT; ++i) {
                float t = fmaf(p.x, qx[i], p.w);
                t = fmaf(p.y, qy[i], t);
                t = fmaf(p.z, qz[i], t);
                mn[i] = fminf(mn[i], t);
            }
        }
    }
#pragma unroll
    for (int i = 0; i < FIPT; ++i)
        if (qi[i] < Nq) atomicMin((int*)&o[qi[i]], __float_as_int(mn[i] + qs[i]));
}

extern "C" void kernel_launch(void* const* d_in, const int* in_sizes, int n_in,
                              void* d_out, int out_size, void* d_ws, size_t ws_size,
                              hipStream_t stream) {
    const float* p1 = (const float*)d_in[0];
    const float* p2 = (const float*)d_in[1];
    float* out = (float*)d_out;

    const int B = 16;
    const int N = in_sizes[0] / (B * 3);
    const int M = in_sizes[1] / (B * 3);

    // init outputs to large positive float (0x7f7f7f7f ~ 3.39e38) for atomicMin
    hipMemsetAsync(d_out, 0x7f, (size_t)out_size * sizeof(float), stream);

    const bool mfma_ok = (N == M) && (N % RPB == 0) && ((N / SPLIT) % CHUNK == 0);

    if (mfma_ok) {
        dim3 grid(N / RPB, B, 2 * SPLIT);
        nnd_mfma3<<<grid, TPB, 0, stream>>>(p1, p2, out, B, N, M);
    } else {
        const int qmax = (N > M) ? N : M;
        dim3 grid((qmax + FTPB * FIPT - 1) / (FTPB * FIPT), B, 2 * FSPLIT);
        nnd_fold<<<grid, FTPB, 0, stream>>>(p1, p2, out, B, N, M);
    }
}